// Round 1
// baseline (3632.223 us; speedup 1.0000x reference)
//
#include <hip/hip_runtime.h>

// Problem constants
#define TSTEPS 128
#define HH1 128
#define HH2 64
#define NCLS 11
#define BTILE 8
// ws layout (floats): WT1 [32][512][4] | WT2a [32][256][4] | WT2b [16][256][4]
#define WT1_ELEMS (32 * 512 * 4)
#define WT2A_ELEMS (32 * 256 * 4)
#define WT2B_ELEMS (16 * 256 * 4)

__device__ __forceinline__ float sigm(float x) { return 1.0f / (1.0f + __expf(-x)); }
__device__ __forceinline__ float tanhf_(float x) { return 1.0f - 2.0f / (__expf(2.0f * x) + 1.0f); }

// Re-pack weights into K-blocked-4, row-minor layout so that the main kernel's
// float4 weight loads are lane-coalesced:  WT[kc][row][0..3] = W[row][kc*4 + kk]
__global__ void prep_weights(const float* __restrict__ Whh1,
                             const float* __restrict__ Wih2,
                             const float* __restrict__ Whh2,
                             float* __restrict__ ws) {
    int tid = blockIdx.x * blockDim.x + threadIdx.x;
    if (tid < WT1_ELEMS) {
        int kk = tid & 3, j = (tid >> 2) & 511, kc = tid >> 11;
        ws[tid] = Whh1[j * 128 + kc * 4 + kk];
    } else if (tid < WT1_ELEMS + WT2A_ELEMS) {
        int t = tid - WT1_ELEMS;
        int kk = t & 3, j = (t >> 2) & 255, kc = t >> 10;
        ws[tid] = Wih2[j * 128 + kc * 4 + kk];
    } else if (tid < WT1_ELEMS + WT2A_ELEMS + WT2B_ELEMS) {
        int t = tid - (WT1_ELEMS + WT2A_ELEMS);
        int kk = t & 3, j = (t >> 2) & 255, kc = t >> 10;
        ws[tid] = Whh2[j * 64 + kc * 4 + kk];
    }
}

// Persistent fused 2-layer LSTM + FC.
// grid = 256 blocks (1/CU), block = 1024 threads (16 waves, 4/SIMD).
// Thread role L1: (b = tid>>7, d = tid&127) owns h-dim d of batch b: all 4 gate rows.
// Thread role L2: lower half (tid<512): (b2, d2) elementwise + K[0..96); upper half: K[96..192) partials.
__global__ __launch_bounds__(1024) void lstm_fused(
    const float* __restrict__ x, const float* __restrict__ Wih1,
    const float* __restrict__ Wfc, const float* __restrict__ bfc,
    const float* __restrict__ ws, float* __restrict__ out) {
    const float4* __restrict__ w1 = (const float4*)ws;                  // [32][512] float4
    const float4* __restrict__ w2a = (const float4*)(ws + WT1_ELEMS);   // [32][256] float4
    const float4* __restrict__ w2b = (const float4*)(ws + WT1_ELEMS + WT2A_ELEMS); // [16][256] float4

    __shared__ float lx[BTILE][2 * TSTEPS];   // x staged: [b][c*128+t]
    __shared__ float lh1[BTILE][HH1];
    __shared__ float lh2[BTILE][HH2];
    __shared__ float gpart[BTILE][HH2][4];    // upper-half partial gate sums

    const int tid = threadIdx.x;
    const int b0 = blockIdx.x * BTILE;

    // stage x for this block's 8 batch rows (coalesced)
    for (int i = tid; i < BTILE * 2 * TSTEPS; i += 1024)
        lx[i >> 8][i & 255] = x[b0 * 256 + i];
    // zero initial states
    lh1[tid >> 7][tid & 127] = 0.0f;
    if (tid < BTILE * HH2) lh2[tid >> 6][tid & 63] = 0.0f;

    const int b = tid >> 7, d = tid & 127;
    const int half = tid >> 9;
    const int b2 = (tid & 511) >> 6, d2 = tid & 63;

    float c1 = 0.0f, c2 = 0.0f;
    float facc[NCLS];
#pragma unroll
    for (int c = 0; c < NCLS; ++c) facc[c] = 0.0f;

    // per-thread input-projection weights (D_IN = 2), PyTorch gate order i,f,g,o
    const float wia = Wih1[2 * d],         wib = Wih1[2 * d + 1];
    const float wfa = Wih1[2 * (128 + d)], wfb = Wih1[2 * (128 + d) + 1];
    const float wga = Wih1[2 * (256 + d)], wgb = Wih1[2 * (256 + d) + 1];
    const float woa = Wih1[2 * (384 + d)], wob = Wih1[2 * (384 + d) + 1];

    // hoisted weight bases (lane-coalesced float4 rows)
    const float4* __restrict__ w1d  = w1 + d;
    const float4* __restrict__ w2ad = w2a + d2;
    const float4* __restrict__ w2bd = w2b + d2;

    __syncthreads();

    for (int t = 0; t < TSTEPS; ++t) {
        // ---- layer 1: gates for (b, d) ----
        const float x0 = lx[b][t], x1 = lx[b][TSTEPS + t];
        float gi = wia * x0 + wib * x1;
        float gf = wfa * x0 + wfb * x1;
        float gg = wga * x0 + wgb * x1;
        float go = woa * x0 + wob * x1;
        const float4* hv = (const float4*)lh1[b];
#pragma unroll 4
        for (int kc = 0; kc < 32; ++kc) {
            const float4 h4 = hv[kc];                 // LDS broadcast (wave-uniform)
            const float4 wi4 = w1d[kc * 512];
            const float4 wf4 = w1d[kc * 512 + 128];
            const float4 wg4 = w1d[kc * 512 + 256];
            const float4 wo4 = w1d[kc * 512 + 384];
            gi += h4.x * wi4.x + h4.y * wi4.y + h4.z * wi4.z + h4.w * wi4.w;
            gf += h4.x * wf4.x + h4.y * wf4.y + h4.z * wf4.z + h4.w * wf4.w;
            gg += h4.x * wg4.x + h4.y * wg4.y + h4.z * wg4.z + h4.w * wg4.w;
            go += h4.x * wo4.x + h4.y * wo4.y + h4.z * wo4.z + h4.w * wo4.w;
        }
        const float i1 = sigm(gi), f1 = sigm(gf), g1v = tanhf_(gg), o1 = sigm(go);
        c1 = f1 * c1 + i1 * g1v;
        const float h1n = o1 * tanhf_(c1);
        __syncthreads();                 // A: all reads of old lh1 done
        lh1[b][d] = h1n;
        __syncthreads();                 // B: new lh1 visible

        // ---- layer 2: K = 128 (h1 new) + 64 (h2 old), split 96/96 across halves ----
        float a0 = 0.0f, a1 = 0.0f, a2 = 0.0f, a3 = 0.0f;
        const float4* h1v = (const float4*)lh1[b2];
        if (half == 0) {
#pragma unroll 4
            for (int kc = 0; kc < 24; ++kc) {
                const float4 h4 = h1v[kc];
                const float4 q0 = w2ad[kc * 256];
                const float4 q1 = w2ad[kc * 256 + 64];
                const float4 q2 = w2ad[kc * 256 + 128];
                const float4 q3 = w2ad[kc * 256 + 192];
                a0 += h4.x * q0.x + h4.y * q0.y + h4.z * q0.z + h4.w * q0.w;
                a1 += h4.x * q1.x + h4.y * q1.y + h4.z * q1.z + h4.w * q1.w;
                a2 += h4.x * q2.x + h4.y * q2.y + h4.z * q2.z + h4.w * q2.w;
                a3 += h4.x * q3.x + h4.y * q3.y + h4.z * q3.z + h4.w * q3.w;
            }
        } else {
#pragma unroll
            for (int kc = 24; kc < 32; ++kc) {
                const float4 h4 = h1v[kc];
                const float4 q0 = w2ad[kc * 256];
                const float4 q1 = w2ad[kc * 256 + 64];
                const float4 q2 = w2ad[kc * 256 + 128];
                const float4 q3 = w2ad[kc * 256 + 192];
                a0 += h4.x * q0.x + h4.y * q0.y + h4.z * q0.z + h4.w * q0.w;
                a1 += h4.x * q1.x + h4.y * q1.y + h4.z * q1.z + h4.w * q1.w;
                a2 += h4.x * q2.x + h4.y * q2.y + h4.z * q2.z + h4.w * q2.w;
                a3 += h4.x * q3.x + h4.y * q3.y + h4.z * q3.z + h4.w * q3.w;
            }
            const float4* h2v = (const float4*)lh2[b2];
#pragma unroll 4
            for (int kc = 0; kc < 16; ++kc) {
                const float4 h4 = h2v[kc];
                const float4 q0 = w2bd[kc * 256];
                const float4 q1 = w2bd[kc * 256 + 64];
                const float4 q2 = w2bd[kc * 256 + 128];
                const float4 q3 = w2bd[kc * 256 + 192];
                a0 += h4.x * q0.x + h4.y * q0.y + h4.z * q0.z + h4.w * q0.w;
                a1 += h4.x * q1.x + h4.y * q1.y + h4.z * q1.z + h4.w * q1.w;
                a2 += h4.x * q2.x + h4.y * q2.y + h4.z * q2.z + h4.w * q2.w;
                a3 += h4.x * q3.x + h4.y * q3.y + h4.z * q3.z + h4.w * q3.w;
            }
            gpart[b2][d2][0] = a0; gpart[b2][d2][1] = a1;
            gpart[b2][d2][2] = a2; gpart[b2][d2][3] = a3;
        }
        __syncthreads();                 // C: partials ready; all lh2 reads done

        if (half == 0) {
            a0 += gpart[b2][d2][0]; a1 += gpart[b2][d2][1];
            a2 += gpart[b2][d2][2]; a3 += gpart[b2][d2][3];
            const float i2 = sigm(a0), f2 = sigm(a1), g2v = tanhf_(a2), o2 = sigm(a3);
            c2 = f2 * c2 + i2 * g2v;
            const float h2n = o2 * tanhf_(c2);
            lh2[b2][d2] = h2n;           // safe: next reads are after next iter's barrier B
            // fused FC accumulation: out[b][c] += h2[t][d2] * Wfc[c][t*64+d2]
            const float* wfc = Wfc + t * 64 + d2;
#pragma unroll
            for (int c = 0; c < NCLS; ++c) facc[c] += h2n * wfc[c * 8192];
        }
    }

    // final FC reduction over d2 lanes (each lower-half wave == one batch row)
    if (half == 0) {
#pragma unroll
        for (int c = 0; c < NCLS; ++c) {
            float v = facc[c];
            v += __shfl_down(v, 32); v += __shfl_down(v, 16);
            v += __shfl_down(v, 8);  v += __shfl_down(v, 4);
            v += __shfl_down(v, 2);  v += __shfl_down(v, 1);
            facc[c] = v;
        }
        if (d2 == 0) {
#pragma unroll
            for (int c = 0; c < NCLS; ++c)
                out[(b0 + b2) * NCLS + c] = facc[c] + bfc[c];
        }
    }
}

extern "C" void kernel_launch(void* const* d_in, const int* in_sizes, int n_in,
                              void* d_out, int out_size, void* d_ws, size_t ws_size,
                              hipStream_t stream) {
    const float* x    = (const float*)d_in[0];
    const float* Wih1 = (const float*)d_in[1];
    const float* Whh1 = (const float*)d_in[2];
    const float* Wih2 = (const float*)d_in[3];
    const float* Whh2 = (const float*)d_in[4];
    const float* Wfc  = (const float*)d_in[5];
    const float* bfc  = (const float*)d_in[6];
    float* out = (float*)d_out;
    float* ws  = (float*)d_ws;

    const int prep_elems = WT1_ELEMS + WT2A_ELEMS + WT2B_ELEMS;
    prep_weights<<<(prep_elems + 255) / 256, 256, 0, stream>>>(Whh1, Wih2, Whh2, ws);
    lstm_fused<<<256, 1024, 0, stream>>>(x, Wih1, Wfc, bfc, ws, out);
}